// Round 15
// baseline (470.247 us; speedup 1.0000x reference)
//
#include <hip/hip_runtime.h>
#include <math.h>

#define N_NODES 100000
#define N_PAD   100352
#define N_EDGES 1600000
#define DIN 256

// CSR bucket-partition parameters
#define NB 782        // buckets of 128 dst nodes
#define NC 256        // edge chunks
#define CHUNK 6250    // N_EDGES / NC exactly
#define MT_N (NB * NC)  // 200192 = 782*256 (scan1 blocks align with bucket rows)
#define MT_PAD 200448

typedef unsigned short u16;
typedef unsigned char u8;
typedef unsigned int u32;
typedef __attribute__((ext_vector_type(8))) short bf16x8;
typedef __attribute__((ext_vector_type(8))) unsigned short us8;
typedef __attribute__((ext_vector_type(4))) float f32x4;
typedef __attribute__((ext_vector_type(2))) float f32x2;

__device__ __forceinline__ float b2f(u16 u) {
    union { unsigned int i; float f; } c; c.i = ((unsigned int)u) << 16; return c.f;
}
__device__ __forceinline__ u16 f2b(float f) {
    union { float f; unsigned int i; } c; c.f = f;
    unsigned int x = c.i;
    return (u16)((x + 0x7fffu + ((x >> 16) & 1u)) >> 16);   // RNE
}
// hardware fp8 e4m3 (OCP on gfx950) encode/decode — both sides HW, so consistent
__device__ __forceinline__ u8 f32_to_fp8(float v) {
    return (u8)(__builtin_amdgcn_cvt_pk_fp8_f32(v, 0.0f, 0, false) & 0xff);
}
__device__ __forceinline__ void accum16(float* a, uint4 v) {  // 16 fp8 -> += 16 f32
    unsigned int w[4] = { v.x, v.y, v.z, v.w };
    #pragma unroll
    for (int q = 0; q < 4; ++q) {
        f32x2 lo = __builtin_amdgcn_cvt_pk_f32_fp8(w[q], false);
        f32x2 hi = __builtin_amdgcn_cvt_pk_f32_fp8(w[q], true);
        a[q * 4 + 0] += lo[0]; a[q * 4 + 1] += lo[1];
        a[q * 4 + 2] += hi[0]; a[q * 4 + 3] += hi[1];
    }
}
__device__ __forceinline__ void accum8(float* a, uint2 v) {   // 8 fp8 -> += 8 f32
    unsigned int w[2] = { v.x, v.y };
    #pragma unroll
    for (int q = 0; q < 2; ++q) {
        f32x2 lo = __builtin_amdgcn_cvt_pk_f32_fp8(w[q], false);
        f32x2 hi = __builtin_amdgcn_cvt_pk_f32_fp8(w[q], true);
        a[q * 4 + 0] += lo[0]; a[q * 4 + 1] += lo[1];
        a[q * 4 + 2] += hi[0]; a[q * 4 + 3] += hi[1];
    }
}

// async global->LDS, 16B per lane; lds base must be wave-uniform
__device__ __forceinline__ void gload_lds16(const u16* g, u16* lds_base) {
    __builtin_amdgcn_global_load_lds(
        (const __attribute__((address_space(1))) void*)g,
        (__attribute__((address_space(3))) void*)lds_base, 16, 0, 0);
}

// m204 bijective XCD-chunk swizzle: contiguous u-ranges land on one XCD,
// so u and u+1 (the two col-blocks of a row-block) share that XCD's L2.
__device__ __forceinline__ u32 xcd_chunk(u32 orig, u32 nwg) {
    u32 q = nwg >> 3, r = nwg & 7;
    u32 xcd = orig & 7, idx = orig >> 3;
    u32 base = (xcd < r) ? xcd * (q + 1) : r * (q + 1) + (xcd - r) * q;
    return base + idx;
}

// ---------------- fused: p1 histogram + 6 weight cvts + x cvt (bf16+fp8) -----------
// blocks [0,NC): histogram (runs FIRST, overlaps with x conversion);
// [NC, NC+320): weights; [NC+320, ...): x
__global__ void cvt_hist_kernel(const float* __restrict__ x, u16* __restrict__ xb,
                                u8* __restrict__ x8,
                                const float* __restrict__ Wl0, const float* __restrict__ Wr0,
                                const float* __restrict__ Wl1, const float* __restrict__ Wr1,
                                const float* __restrict__ Wl2, const float* __restrict__ Wr2,
                                u16* __restrict__ wl0, u16* __restrict__ wr0,
                                u16* __restrict__ wl1, u16* __restrict__ wr1,
                                u16* __restrict__ wl2, u16* __restrict__ wr2,
                                const int* __restrict__ dst, int* __restrict__ MT) {
    __shared__ int bins[NB];
    int b = blockIdx.x;
    if (b < NC) {
        const int c = b, tid = threadIdx.x;
        for (int i = tid; i < NB; i += 256) bins[i] = 0;
        __syncthreads();
        const int e0 = c * CHUNK;
        for (int e = e0 + tid; e < e0 + CHUNK; e += 256)
            atomicAdd(&bins[dst[e] >> 7], 1);
        __syncthreads();
        for (int i = tid; i < NB; i += 256) MT[i * NC + c] = bins[i];
        return;
    }
    b -= NC;
    if (b < 320) {
        const float* s; u16* d; int i;
        if (b < 64)       { s = Wl0; d = wl0; i = b * 256 + threadIdx.x; }
        else if (b < 128) { s = Wr0; d = wr0; i = (b - 64) * 256 + threadIdx.x; }
        else if (b < 192) { s = Wl1; d = wl1; i = (b - 128) * 256 + threadIdx.x; }
        else if (b < 256) { s = Wr1; d = wr1; i = (b - 192) * 256 + threadIdx.x; }
        else if (b < 288) { s = Wl2; d = wl2; i = (b - 256) * 256 + threadIdx.x; }
        else              { s = Wr2; d = wr2; i = (b - 288) * 256 + threadIdx.x; }
        float4 v = ((const float4*)s)[i];
        ushort4 o;
        o.x = f2b(v.x); o.y = f2b(v.y); o.z = f2b(v.z); o.w = f2b(v.w);
        ((ushort4*)d)[i] = o;
        return;
    }
    b -= 320;
    int i = b * 256 + threadIdx.x;
    if (i < N_NODES * 64) {
        float4 v = ((const float4*)x)[i];
        ushort4 o;
        o.x = f2b(v.x); o.y = f2b(v.y); o.z = f2b(v.z); o.w = f2b(v.w);
        ((ushort4*)xb)[i] = o;
        u32 r = __builtin_amdgcn_cvt_pk_fp8_f32(v.x, v.y, 0, false);
        r = __builtin_amdgcn_cvt_pk_fp8_f32(v.z, v.w, r, true);
        ((u32*)x8)[i] = r;
    }
}

// ---------------- CSR build: scans (bucket-row aligned; no scan3 pass) -------------
__global__ void scan1_kernel(const int* __restrict__ in, int* __restrict__ excl,
                             int* __restrict__ blocksums, int n) {
    __shared__ int s[256];
    int tid = threadIdx.x;
    int i = blockIdx.x * 256 + tid;
    int v = (i < n) ? in[i] : 0;
    s[tid] = v;
    __syncthreads();
    for (int off = 1; off < 256; off <<= 1) {
        int t = (tid >= off) ? s[tid - off] : 0;
        __syncthreads();
        s[tid] += t;
        __syncthreads();
    }
    if (i < n) excl[i] = s[tid] - v;
    if (tid == 255) blocksums[blockIdx.x] = s[255];
}

__global__ void scan_carry_kernel(int* __restrict__ bsums, int nb) {
    __shared__ int s[256];
    int tid = threadIdx.x;
    int carry = 0;
    for (int base = 0; base < nb; base += 256) {
        int i = base + tid;
        int v = (i < nb) ? bsums[i] : 0;
        s[tid] = v;
        __syncthreads();
        for (int off = 1; off < 256; off <<= 1) {
            int t = (tid >= off) ? s[tid - off] : 0;
            __syncthreads();
            s[tid] += t;
            __syncthreads();
        }
        int incl = s[tid];
        int tot = s[255];
        if (i < nb) bsums[i] = incl - v + carry;
        carry += tot;
        __syncthreads();
    }
}

__launch_bounds__(256)
__global__ void p2_partition(const int* __restrict__ src, const int* __restrict__ dst,
                             const int* __restrict__ MTs, const int* __restrict__ bsums,
                             u32* __restrict__ csr_tmp) {
    __shared__ int cur[NB];
    const int c = blockIdx.x, tid = threadIdx.x;
    for (int b = tid; b < NB; b += 256) cur[b] = MTs[b * NC + c] + bsums[b];
    __syncthreads();
    const int e0 = c * CHUNK;
    for (int e = e0 + tid; e < e0 + CHUNK; e += 256) {
        int d = dst[e];
        int pos = atomicAdd(&cur[d >> 7], 1);   // LDS atomic
        csr_tmp[pos] = ((u32)(d & 127) << 25) | (u32)src[e];
    }
}

__launch_bounds__(256)
__global__ void p3_csr(const int* __restrict__ MTs, const int* __restrict__ bsums,
                       const u32* __restrict__ csr_tmp,
                       int* __restrict__ csr, int* __restrict__ rowptr,
                       int* __restrict__ rowend, float* __restrict__ rinv) {
    __shared__ int cnt[128];
    __shared__ int excl[128];
    __shared__ int cur[128];
    const int b = blockIdx.x, tid = threadIdx.x;
    const int beg = MTs[b * NC] + bsums[b];
    const int end = (b == NB - 1) ? N_EDGES : (MTs[(b + 1) * NC] + bsums[b + 1]);
    if (tid < 128) cnt[tid] = 0;
    __syncthreads();
    for (int e = beg + tid; e < end; e += 256)
        atomicAdd(&cnt[csr_tmp[e] >> 25], 1);
    __syncthreads();
    if (tid == 0) {
        int run = 0;
        for (int i = 0; i < 128; ++i) { excl[i] = run; run += cnt[i]; }
    }
    __syncthreads();
    if (tid < 128) cur[tid] = beg + excl[tid];
    __syncthreads();
    for (int e = beg + tid; e < end; e += 256) {
        u32 v = csr_tmp[e];
        int pos = atomicAdd(&cur[v >> 25], 1);  // LDS atomic
        csr[pos] = (int)(v & 0x1FFFFFFu);
    }
    if (tid < 128) {
        int node = b * 128 + tid;
        if (node < N_NODES) {
            int rp = beg + excl[tid];
            rowptr[node] = rp;
            rowend[node] = rp + cnt[tid];
            rinv[node]   = 1.0f / (float)max(cnt[tid], 1);
        }
    }
}

// ---------------- gather aggregation: fp8 rows (256B), 16 lanes/node ----------------
__launch_bounds__(256)
__global__ void agg_kernel(const int* __restrict__ rowptr, const int* __restrict__ rowend,
                           const int* __restrict__ csr_src, const float* __restrict__ rinv,
                           const u8* __restrict__ h8, u16* __restrict__ agg) {
    int node = blockIdx.x * 16 + (threadIdx.x >> 4);
    int lane = threadIdx.x & 15;
    if (node >= N_NODES) return;
    int beg = rowptr[node];
    int end = rowend[node];
    const u8* hl = h8 + lane * 16;
    float a[16] = {};
    int p = beg;
    for (; p + 3 < end; p += 4) {
        int s0 = csr_src[p], s1 = csr_src[p + 1], s2 = csr_src[p + 2], s3 = csr_src[p + 3];
        uint4 v0 = *(const uint4*)(hl + (size_t)s0 * 256);
        uint4 v1 = *(const uint4*)(hl + (size_t)s1 * 256);
        uint4 v2 = *(const uint4*)(hl + (size_t)s2 * 256);
        uint4 v3 = *(const uint4*)(hl + (size_t)s3 * 256);
        accum16(a, v0); accum16(a, v1); accum16(a, v2); accum16(a, v3);
    }
    for (; p < end; ++p) {
        uint4 v0 = *(const uint4*)(hl + (size_t)csr_src[p] * 256);
        accum16(a, v0);
    }
    float r = rinv[node];
    us8 o0, o1;
    #pragma unroll
    for (int j = 0; j < 8; ++j) { o0[j] = f2b(a[j] * r); o1[j] = f2b(a[8 + j] * r); }
    u16* d = agg + (size_t)node * DIN + lane * 16;
    *(us8*)d = o0;
    *(us8*)(d + 8) = o1;
}

// ---------------- MFMA GEMM: A via LDS (4 slots, lookahead-3); B reg-direct --------
// B (weights) is L2-resident everywhere: lanes load their 4 bf16x8 B-frags straight
// from global into registers, double-buffered (bX/bY, unroll-by-2). LDS holds only
// A: 4 slots x 8KB = 32KB. Per-step issue order [loadB(s+1), stageA(s+3)] keeps the
// vmcnt FIFO clean: waiting vmcnt(8) at step s retires A(s) without forcing
// A(s+1), A(s+2) or B(s) (compiler inserts its own tighter wait for B regs).
// Both-sides XOR swizzle blk = lg ^ ((row>>1)&3) on A. Grid 1D, XCD-chunked.
// MODE 0: DUAL K=512 ([A0|A1]@[B0|B1]^T) bf16 out0 (+fp8 out8), bias+relu.
// MODE 1: K=256: csel==0 -> A0@B0^T -> fp8 out8 (z2); csel==1 -> A0@B1^T+bias -> f32 out1.
template <int MODE>
__launch_bounds__(256)
__global__ void sage_gemm(const u16* __restrict__ A0, const u16* __restrict__ A1,
                          const u16* __restrict__ B0w, const u16* __restrict__ B1w,
                          const float* __restrict__ bias, void* __restrict__ out0,
                          void* __restrict__ out1, u8* __restrict__ out8,
                          int dout, int do_relu) {
    __shared__ u16 sA[4][128 * 32];   // 32 KB

    const u32 u    = xcd_chunk(blockIdx.x, gridDim.x);
    const int csel = u & 1;
    const int row0 = (int)(u >> 1) * 128;
    const int col0 = (MODE == 0) ? csel * 128 : 0;
    const int t    = threadIdx.x;
    const int w    = t >> 6, lane = t & 63;
    const int wr   = w >> 1, wc = w & 1;
    const int lr   = lane & 15, lg = lane >> 4;
    const int srow = lane >> 2;                       // 0..15
    const int sblk = (lane & 3) ^ ((lane >> 3) & 3);  // (srow>>1)&3 swizzle
    const u16* Bsel = csel ? B1w : B0w;
    const int NT = (MODE == 0) ? 16 : 8;

    f32x4 acc[4][4] = {};

    auto stageA = [&](int slot, int tk) {
        const int kt = tk * 32;
        const u16* Asrc = (MODE == 0 && kt >= 256) ? A1 : A0;
        const int  kb   = (MODE == 0 && kt >= 256) ? kt - 256 : kt;
        #pragma unroll
        for (int i = 0; i < 2; ++i) {
            int row = w * 32 + i * 16 + srow;
            gload_lds16(Asrc + (size_t)(row0 + row) * DIN + kb + sblk * 8,
                        &sA[slot][w * 1024 + i * 512]);
        }
    };
    auto loadB = [&](int tk, bf16x8* dst) {
        const int kt = tk * 32;
        const u16* Bsrc = (MODE == 0) ? ((kt >= 256) ? B1w : B0w) : Bsel;
        const int kb = (MODE == 0 && kt >= 256) ? kt - 256 : kt;
        #pragma unroll
        for (int n = 0; n < 4; ++n)
            dst[n] = *(const bf16x8*)(Bsrc +
                (size_t)(col0 + wc * 64 + n * 16 + lr) * DIN + kb + lg * 8);
    };
    auto dsreadA = [&](int slot, bf16x8* af) {
        #pragma unroll
        for (int m = 0; m < 4; ++m) {
            int row = wr * 64 + m * 16 + lr;
            af[m] = *(const bf16x8*)&sA[slot][row * 32 + 8 * (lg ^ ((lr >> 1) & 3))];
        }
    };
    auto mfma16 = [&](bf16x8* af, bf16x8* bfr) {
        #pragma unroll
        for (int m = 0; m < 4; ++m)
            #pragma unroll
            for (int n = 0; n < 4; ++n)
                acc[m][n] = __builtin_amdgcn_mfma_f32_16x16x32_bf16(af[m], bfr[n], acc[m][n], 0, 0, 0);
    };

    // prologue: A 3 deep, B(0) in regs
    stageA(0, 0); stageA(1, 1); stageA(2, 2);
    bf16x8 bX[4], bY[4], af[4];
    loadB(0, bX);

    int cur = 0;
    for (int tk = 0; tk < NT; tk += 2) {
        // ---------- even step s = tk: consume bX, prefetch bY ----------
        if (tk + 2 < NT)      asm volatile("s_waitcnt vmcnt(8)" ::: "memory");
        else if (tk + 1 < NT) asm volatile("s_waitcnt vmcnt(6)" ::: "memory");
        else                  asm volatile("s_waitcnt vmcnt(4)" ::: "memory");
        __builtin_amdgcn_sched_barrier(0);
        __builtin_amdgcn_s_barrier();         // all waves: A(tk) resident in sA[cur]
        __builtin_amdgcn_sched_barrier(0);
        if (tk + 1 < NT) loadB(tk + 1, bY);
        if (tk + 3 < NT) stageA((cur + 3) & 3, tk + 3);
        dsreadA(cur, af);
        mfma16(af, bX);
        cur = (cur + 1) & 3;

        // ---------- odd step s = tk+1: consume bY, prefetch bX ----------
        if (tk + 1 < NT) {
            const int s = tk + 1;
            if (s + 2 < NT)      asm volatile("s_waitcnt vmcnt(8)" ::: "memory");
            else if (s + 1 < NT) asm volatile("s_waitcnt vmcnt(6)" ::: "memory");
            else                 asm volatile("s_waitcnt vmcnt(4)" ::: "memory");
            __builtin_amdgcn_sched_barrier(0);
            __builtin_amdgcn_s_barrier();
            __builtin_amdgcn_sched_barrier(0);
            if (s + 1 < NT) loadB(s + 1, bX);
            if (s + 3 < NT) stageA((cur + 3) & 3, s + 3);
            dsreadA(cur, af);
            mfma16(af, bY);
            cur = (cur + 1) & 3;
        }
    }

    const bool f32out = (MODE == 1) && (csel == 1);
    #pragma unroll
    for (int m = 0; m < 4; ++m) {
        int row = row0 + wr * 64 + m * 16 + lg * 4;
        #pragma unroll
        for (int n = 0; n < 4; ++n) {
            int col = col0 + wc * 64 + n * 16 + lr;
            #pragma unroll
            for (int r = 0; r < 4; ++r) {
                float v = acc[m][n][r];
                if (MODE == 0) {
                    v += bias[col];
                    if (do_relu) v = fmaxf(v, 0.0f);
                    ((u16*)out0)[(size_t)(row + r) * dout + col] = f2b(v);
                    if (out8) out8[(size_t)(row + r) * dout + col] = f32_to_fp8(v);
                } else if (f32out) {
                    v += bias[col];
                    ((float*)out1)[(size_t)(row + r) * dout + col] = v;
                } else {
                    out8[(size_t)(row + r) * dout + col] = f32_to_fp8(v);
                }
            }
        }
    }
}

// ---------------- fused layer-2 agg + classifier: fp8 z2 rows (128B) ----------------
__launch_bounds__(256)
__global__ void aggcls_kernel(const int* __restrict__ rowptr, const int* __restrict__ rowend,
                              const int* __restrict__ csr_src, const float* __restrict__ rinv,
                              const u8* __restrict__ z28, const float* __restrict__ y2,
                              const float* __restrict__ Wc, const float* __restrict__ bc,
                              float* __restrict__ out) {
    __shared__ float sW[128];
    int t = threadIdx.x;
    if (t < 128) sW[t] = Wc[t];
    __syncthreads();
    int node = blockIdx.x * 16 + (t >> 4);
    int lane = t & 15;
    if (node >= N_NODES) return;
    int beg = rowptr[node];
    int end = rowend[node];
    const u8* zl = z28 + lane * 8;
    float a[8] = {};
    int p = beg;
    for (; p + 3 < end; p += 4) {
        int s0 = csr_src[p], s1 = csr_src[p + 1], s2 = csr_src[p + 2], s3 = csr_src[p + 3];
        uint2 v0 = *(const uint2*)(zl + (size_t)s0 * 128);
        uint2 v1 = *(const uint2*)(zl + (size_t)s1 * 128);
        uint2 v2 = *(const uint2*)(zl + (size_t)s2 * 128);
        uint2 v3 = *(const uint2*)(zl + (size_t)s3 * 128);
        accum8(a, v0); accum8(a, v1); accum8(a, v2); accum8(a, v3);
    }
    for (; p < end; ++p) {
        uint2 v0 = *(const uint2*)(zl + (size_t)csr_src[p] * 128);
        accum8(a, v0);
    }
    float r = rinv[node];
    float4 ylo = *(const float4*)(y2 + (size_t)node * 128 + lane * 8);
    float4 yhi = *(const float4*)(y2 + (size_t)node * 128 + lane * 8 + 4);
    float yv[8] = { ylo.x, ylo.y, ylo.z, ylo.w, yhi.x, yhi.y, yhi.z, yhi.w };
    float s = 0.f;
    #pragma unroll
    for (int j = 0; j < 8; ++j)
        s += (a[j] * r + yv[j]) * sW[lane * 8 + j];
    #pragma unroll
    for (int off = 8; off; off >>= 1) s += __shfl_xor(s, off, 16);
    if (lane == 0) {
        float z = s + bc[0];
        out[node] = 1.0f / (1.0f + expf(-z));
    }
}

extern "C" void kernel_launch(void* const* d_in, const int* in_sizes, int n_in,
                              void* d_out, int out_size, void* d_ws, size_t ws_size,
                              hipStream_t stream) {
    const float* x   = (const float*)d_in[0];
    const int*   ei  = (const int*)d_in[1];
    const float* Wl0 = (const float*)d_in[2];
    const float* Wr0 = (const float*)d_in[3];
    const float* b0  = (const float*)d_in[4];
    const float* Wl1 = (const float*)d_in[5];
    const float* Wr1 = (const float*)d_in[6];
    const float* b1  = (const float*)d_in[7];
    const float* Wl2 = (const float*)d_in[8];
    const float* Wr2 = (const float*)d_in[9];
    const float* b2  = (const float*)d_in[10];
    const float* Wc  = (const float*)d_in[11];
    const float* bc  = (const float*)d_in[12];
    float* out = (float*)d_out;

    const int* src = ei;
    const int* dst = ei + N_EDGES;

    // ---- workspace layout ----
    int*   MT     = (int*)d_ws;                    // MT_PAD
    int*   MTs    = MT + MT_PAD;                   // MT_PAD
    int*   bsums  = MTs + MT_PAD;                  // 1024
    u32*   csrtmp = (u32*)(bsums + 1024);          // N_EDGES
    int*   csr    = (int*)(csrtmp + N_EDGES);      // N_EDGES
    int*   rowptr = csr + N_EDGES;                 // N_PAD
    int*   rowend = rowptr + N_PAD;                // N_PAD
    float* rinv   = (float*)(rowend + N_PAD);      // N_PAD
    u16*   xb     = (u16*)(rinv + N_PAD);          // N_PAD*256 bf16
    u16*   wb     = xb + (size_t)N_PAD * 256;      // weights
    u16*   bufA   = wb + 327680;                   // agg (bf16)
    u16*   bufB   = bufA + (size_t)N_PAD * 256;    // h1 / y2(f32,128)
    u16*   bufC   = bufB + (size_t)N_PAD * 256;    // h2
    u8*    x8     = (u8*)(bufC + (size_t)N_PAD * 256);  // N_PAD*256 fp8
    u8*    h18    = x8 + (size_t)N_PAD * 256;           // N_PAD*256 fp8
    u8*    z28    = h18 + (size_t)N_PAD * 256;          // N_PAD*128 fp8

    u16* wl0 = wb;
    u16* wr0 = wl0 + 65536;
    u16* wl1 = wr0 + 65536;
    u16* wr1 = wl1 + 65536;
    u16* wl2 = wr1 + 65536;
    u16* wr2 = wl2 + 32768;

    // ---- conversions + histogram (hist blocks FIRST so they overlap cvt) ----
    const int xblocks = (N_NODES * 64 + 255) / 256;   // 25000
    cvt_hist_kernel<<<NC + 320 + xblocks, 256, 0, stream>>>(
        x, xb, x8, Wl0, Wr0, Wl1, Wr1, Wl2, Wr2,
        wl0, wr0, wl1, wr1, wl2, wr2, dst, MT);

    // ---- CSR build (scan1 blocks == bucket rows; carry folded into p2/p3) ----
    const int scan_blocks = MT_N / 256;            // 782 == NB
    scan1_kernel<<<scan_blocks, 256, 0, stream>>>(MT, MTs, bsums, MT_N);
    scan_carry_kernel<<<1, 256, 0, stream>>>(bsums, scan_blocks);
    p2_partition<<<NC, 256, 0, stream>>>(src, dst, MTs, bsums, csrtmp);
    p3_csr<<<NB, 256, 0, stream>>>(MTs, bsums, csrtmp, csr, rowptr, rowend, rinv);

    const int Mblocks = (N_NODES + 127) / 128;     // 782
    const int gemm_blocks = Mblocks * 2;           // 1564 (1D, xcd-chunked)
    const int agg_blocks = (N_NODES + 15) / 16;    // 6250

    // ---- layer 0 ----
    agg_kernel<<<agg_blocks, 256, 0, stream>>>(rowptr, rowend, csr, rinv, x8, bufA);
    sage_gemm<0><<<gemm_blocks, 256, 0, stream>>>(bufA, xb, wl0, wr0, b0, bufB, nullptr, h18, 256, 1);

    // ---- layer 1 ----
    agg_kernel<<<agg_blocks, 256, 0, stream>>>(rowptr, rowend, csr, rinv, h18, bufA);
    sage_gemm<0><<<gemm_blocks, 256, 0, stream>>>(bufA, bufB, wl1, wr1, b1, bufC, nullptr, nullptr, 256, 1);

    // ---- layer 2, projection-first (agg is linear) ----
    // csel=0: z2 = h2 @ Wl2^T -> fp8 z28 ; csel=1: y2 = h2 @ Wr2^T + b2 -> f32 bufB
    sage_gemm<1><<<gemm_blocks, 256, 0, stream>>>(bufC, nullptr, wl2, wr2, b2, nullptr, bufB, z28, 128, 0);
    // h3 = agg(z2)*rinv + y2, fused with classifier
    aggcls_kernel<<<agg_blocks, 256, 0, stream>>>(rowptr, rowend, csr, rinv,
                                                  z28, (const float*)bufB, Wc, bc, out);
}

// Round 16
// 396.757 us; speedup vs baseline: 1.1852x; 1.1852x over previous
//
#include <hip/hip_runtime.h>
#include <math.h>

#define N_NODES 100000
#define N_PAD   100352
#define N_EDGES 1600000
#define DIN 256

// CSR bucket-partition parameters
#define NB 782        // buckets of 128 dst nodes
#define NC 256        // edge chunks
#define CHUNK 6250    // N_EDGES / NC exactly
#define MT_N (NB * NC)  // 200192 = 782*256 (scan1 blocks align with bucket rows)
#define MT_PAD 200448

typedef unsigned short u16;
typedef unsigned char u8;
typedef unsigned int u32;
typedef __attribute__((ext_vector_type(8))) short bf16x8;
typedef __attribute__((ext_vector_type(8))) unsigned short us8;
typedef __attribute__((ext_vector_type(4))) float f32x4;
typedef __attribute__((ext_vector_type(2))) float f32x2;

__device__ __forceinline__ float b2f(u16 u) {
    union { unsigned int i; float f; } c; c.i = ((unsigned int)u) << 16; return c.f;
}
__device__ __forceinline__ u16 f2b(float f) {
    union { float f; unsigned int i; } c; c.f = f;
    unsigned int x = c.i;
    return (u16)((x + 0x7fffu + ((x >> 16) & 1u)) >> 16);   // RNE
}
// hardware fp8 e4m3 (OCP on gfx950) encode/decode — both sides HW, so consistent
__device__ __forceinline__ u8 f32_to_fp8(float v) {
    return (u8)(__builtin_amdgcn_cvt_pk_fp8_f32(v, 0.0f, 0, false) & 0xff);
}
__device__ __forceinline__ void accum16(float* a, uint4 v) {  // 16 fp8 -> += 16 f32
    unsigned int w[4] = { v.x, v.y, v.z, v.w };
    #pragma unroll
    for (int q = 0; q < 4; ++q) {
        f32x2 lo = __builtin_amdgcn_cvt_pk_f32_fp8(w[q], false);
        f32x2 hi = __builtin_amdgcn_cvt_pk_f32_fp8(w[q], true);
        a[q * 4 + 0] += lo[0]; a[q * 4 + 1] += lo[1];
        a[q * 4 + 2] += hi[0]; a[q * 4 + 3] += hi[1];
    }
}
__device__ __forceinline__ void accum8(float* a, uint2 v) {   // 8 fp8 -> += 8 f32
    unsigned int w[2] = { v.x, v.y };
    #pragma unroll
    for (int q = 0; q < 2; ++q) {
        f32x2 lo = __builtin_amdgcn_cvt_pk_f32_fp8(w[q], false);
        f32x2 hi = __builtin_amdgcn_cvt_pk_f32_fp8(w[q], true);
        a[q * 4 + 0] += lo[0]; a[q * 4 + 1] += lo[1];
        a[q * 4 + 2] += hi[0]; a[q * 4 + 3] += hi[1];
    }
}

// async global->LDS, 16B per lane; lds base must be wave-uniform
__device__ __forceinline__ void gload_lds16(const u16* g, u16* lds_base) {
    __builtin_amdgcn_global_load_lds(
        (const __attribute__((address_space(1))) void*)g,
        (__attribute__((address_space(3))) void*)lds_base, 16, 0, 0);
}

// m204 bijective XCD-chunk swizzle: contiguous u-ranges land on one XCD,
// so u and u+1 (the two col-blocks of a row-block) share that XCD's L2.
__device__ __forceinline__ u32 xcd_chunk(u32 orig, u32 nwg) {
    u32 q = nwg >> 3, r = nwg & 7;
    u32 xcd = orig & 7, idx = orig >> 3;
    u32 base = (xcd < r) ? xcd * (q + 1) : r * (q + 1) + (xcd - r) * q;
    return base + idx;
}

// ---------------- fused: p1 histogram + 6 weight cvts + x cvt (bf16+fp8) -----------
// blocks [0,NC): histogram (runs FIRST, overlaps with x conversion);
// [NC, NC+320): weights; [NC+320, ...): x
__global__ void cvt_hist_kernel(const float* __restrict__ x, u16* __restrict__ xb,
                                u8* __restrict__ x8,
                                const float* __restrict__ Wl0, const float* __restrict__ Wr0,
                                const float* __restrict__ Wl1, const float* __restrict__ Wr1,
                                const float* __restrict__ Wl2, const float* __restrict__ Wr2,
                                u16* __restrict__ wl0, u16* __restrict__ wr0,
                                u16* __restrict__ wl1, u16* __restrict__ wr1,
                                u16* __restrict__ wl2, u16* __restrict__ wr2,
                                const int* __restrict__ dst, int* __restrict__ MT) {
    __shared__ int bins[NB];
    int b = blockIdx.x;
    if (b < NC) {
        const int c = b, tid = threadIdx.x;
        for (int i = tid; i < NB; i += 256) bins[i] = 0;
        __syncthreads();
        const int e0 = c * CHUNK;
        for (int e = e0 + tid; e < e0 + CHUNK; e += 256)
            atomicAdd(&bins[dst[e] >> 7], 1);
        __syncthreads();
        for (int i = tid; i < NB; i += 256) MT[i * NC + c] = bins[i];
        return;
    }
    b -= NC;
    if (b < 320) {
        const float* s; u16* d; int i;
        if (b < 64)       { s = Wl0; d = wl0; i = b * 256 + threadIdx.x; }
        else if (b < 128) { s = Wr0; d = wr0; i = (b - 64) * 256 + threadIdx.x; }
        else if (b < 192) { s = Wl1; d = wl1; i = (b - 128) * 256 + threadIdx.x; }
        else if (b < 256) { s = Wr1; d = wr1; i = (b - 192) * 256 + threadIdx.x; }
        else if (b < 288) { s = Wl2; d = wl2; i = (b - 256) * 256 + threadIdx.x; }
        else              { s = Wr2; d = wr2; i = (b - 288) * 256 + threadIdx.x; }
        float4 v = ((const float4*)s)[i];
        ushort4 o;
        o.x = f2b(v.x); o.y = f2b(v.y); o.z = f2b(v.z); o.w = f2b(v.w);
        ((ushort4*)d)[i] = o;
        return;
    }
    b -= 320;
    int i = b * 256 + threadIdx.x;
    if (i < N_NODES * 64) {
        float4 v = ((const float4*)x)[i];
        ushort4 o;
        o.x = f2b(v.x); o.y = f2b(v.y); o.z = f2b(v.z); o.w = f2b(v.w);
        ((ushort4*)xb)[i] = o;
        u32 r = __builtin_amdgcn_cvt_pk_fp8_f32(v.x, v.y, 0, false);
        r = __builtin_amdgcn_cvt_pk_fp8_f32(v.z, v.w, r, true);
        ((u32*)x8)[i] = r;
    }
}

// ---------------- CSR build: scans (bucket-row aligned; no scan3 pass) -------------
__global__ void scan1_kernel(const int* __restrict__ in, int* __restrict__ excl,
                             int* __restrict__ blocksums, int n) {
    __shared__ int s[256];
    int tid = threadIdx.x;
    int i = blockIdx.x * 256 + tid;
    int v = (i < n) ? in[i] : 0;
    s[tid] = v;
    __syncthreads();
    for (int off = 1; off < 256; off <<= 1) {
        int t = (tid >= off) ? s[tid - off] : 0;
        __syncthreads();
        s[tid] += t;
        __syncthreads();
    }
    if (i < n) excl[i] = s[tid] - v;
    if (tid == 255) blocksums[blockIdx.x] = s[255];
}

__global__ void scan_carry_kernel(int* __restrict__ bsums, int nb) {
    __shared__ int s[256];
    int tid = threadIdx.x;
    int carry = 0;
    for (int base = 0; base < nb; base += 256) {
        int i = base + tid;
        int v = (i < nb) ? bsums[i] : 0;
        s[tid] = v;
        __syncthreads();
        for (int off = 1; off < 256; off <<= 1) {
            int t = (tid >= off) ? s[tid - off] : 0;
            __syncthreads();
            s[tid] += t;
            __syncthreads();
        }
        int incl = s[tid];
        int tot = s[255];
        if (i < nb) bsums[i] = incl - v + carry;
        carry += tot;
        __syncthreads();
    }
}

__launch_bounds__(256)
__global__ void p2_partition(const int* __restrict__ src, const int* __restrict__ dst,
                             const int* __restrict__ MTs, const int* __restrict__ bsums,
                             u32* __restrict__ csr_tmp) {
    __shared__ int cur[NB];
    const int c = blockIdx.x, tid = threadIdx.x;
    for (int b = tid; b < NB; b += 256) cur[b] = MTs[b * NC + c] + bsums[b];
    __syncthreads();
    const int e0 = c * CHUNK;
    for (int e = e0 + tid; e < e0 + CHUNK; e += 256) {
        int d = dst[e];
        int pos = atomicAdd(&cur[d >> 7], 1);   // LDS atomic
        csr_tmp[pos] = ((u32)(d & 127) << 25) | (u32)src[e];
    }
}

__launch_bounds__(256)
__global__ void p3_csr(const int* __restrict__ MTs, const int* __restrict__ bsums,
                       const u32* __restrict__ csr_tmp,
                       int* __restrict__ csr, int* __restrict__ rowptr,
                       int* __restrict__ rowend, float* __restrict__ rinv) {
    __shared__ int cnt[128];
    __shared__ int excl[128];
    __shared__ int cur[128];
    const int b = blockIdx.x, tid = threadIdx.x;
    const int beg = MTs[b * NC] + bsums[b];
    const int end = (b == NB - 1) ? N_EDGES : (MTs[(b + 1) * NC] + bsums[b + 1]);
    if (tid < 128) cnt[tid] = 0;
    __syncthreads();
    for (int e = beg + tid; e < end; e += 256)
        atomicAdd(&cnt[csr_tmp[e] >> 25], 1);
    __syncthreads();
    if (tid == 0) {
        int run = 0;
        for (int i = 0; i < 128; ++i) { excl[i] = run; run += cnt[i]; }
    }
    __syncthreads();
    if (tid < 128) cur[tid] = beg + excl[tid];
    __syncthreads();
    for (int e = beg + tid; e < end; e += 256) {
        u32 v = csr_tmp[e];
        int pos = atomicAdd(&cur[v >> 25], 1);  // LDS atomic
        csr[pos] = (int)(v & 0x1FFFFFFu);
    }
    if (tid < 128) {
        int node = b * 128 + tid;
        if (node < N_NODES) {
            int rp = beg + excl[tid];
            rowptr[node] = rp;
            rowend[node] = rp + cnt[tid];
            rinv[node]   = 1.0f / (float)max(cnt[tid], 1);
        }
    }
}

// ---------------- gather aggregation: fp8 rows (256B), 16 lanes/node ----------------
__launch_bounds__(256)
__global__ void agg_kernel(const int* __restrict__ rowptr, const int* __restrict__ rowend,
                           const int* __restrict__ csr_src, const float* __restrict__ rinv,
                           const u8* __restrict__ h8, u16* __restrict__ agg) {
    int node = blockIdx.x * 16 + (threadIdx.x >> 4);
    int lane = threadIdx.x & 15;
    if (node >= N_NODES) return;
    int beg = rowptr[node];
    int end = rowend[node];
    const u8* hl = h8 + lane * 16;
    float a[16] = {};
    int p = beg;
    for (; p + 3 < end; p += 4) {
        int s0 = csr_src[p], s1 = csr_src[p + 1], s2 = csr_src[p + 2], s3 = csr_src[p + 3];
        uint4 v0 = *(const uint4*)(hl + (size_t)s0 * 256);
        uint4 v1 = *(const uint4*)(hl + (size_t)s1 * 256);
        uint4 v2 = *(const uint4*)(hl + (size_t)s2 * 256);
        uint4 v3 = *(const uint4*)(hl + (size_t)s3 * 256);
        accum16(a, v0); accum16(a, v1); accum16(a, v2); accum16(a, v3);
    }
    for (; p < end; ++p) {
        uint4 v0 = *(const uint4*)(hl + (size_t)csr_src[p] * 256);
        accum16(a, v0);
    }
    float r = rinv[node];
    us8 o0, o1;
    #pragma unroll
    for (int j = 0; j < 8; ++j) { o0[j] = f2b(a[j] * r); o1[j] = f2b(a[8 + j] * r); }
    u16* d = agg + (size_t)node * DIN + lane * 16;
    *(us8*)d = o0;
    *(us8*)(d + 8) = o1;
}

// ---------------- MFMA GEMM: BK=32, counted-vmcnt pipeline, 3 blocks/CU ------------
// r13-exact structure (best measured: 64.3 us) + __launch_bounds__(256,3) to force
// the register allocator to fit 3 co-resident blocks/CU (12 waves/CU): the third
// block covers the barrier-drain windows the other two leave.
// LDS tiles linear [128][32] u16 (32KB total). Both-sides XOR swizzle
// blk = lg ^ ((row>>1)&3): worst 2-way (free). Grid 1D 2*Mblocks, XCD-chunked.
// MODE 0: DUAL K=512 ([A0|A1]@[B0|B1]^T) bf16 out0 (+fp8 out8), bias+relu.
// MODE 1: K=256: csel==0 -> A0@B0^T -> fp8 out8 (z2); csel==1 -> A0@B1^T+bias -> f32 out1.
template <int MODE>
__launch_bounds__(256, 3)
__global__ void sage_gemm(const u16* __restrict__ A0, const u16* __restrict__ A1,
                          const u16* __restrict__ B0w, const u16* __restrict__ B1w,
                          const float* __restrict__ bias, void* __restrict__ out0,
                          void* __restrict__ out1, u8* __restrict__ out8,
                          int dout, int do_relu) {
    __shared__ u16 sA[2][128 * 32];
    __shared__ u16 sB[2][128 * 32];

    const u32 u    = xcd_chunk(blockIdx.x, gridDim.x);
    const int csel = u & 1;
    const int row0 = (int)(u >> 1) * 128;
    const int col0 = (MODE == 0) ? csel * 128 : 0;
    const int t    = threadIdx.x;
    const int w    = t >> 6, lane = t & 63;
    const int wr   = w >> 1, wc = w & 1;
    const int lr   = lane & 15, lg = lane >> 4;
    const int srow = lane >> 2;                       // 0..15
    const int sblk = (lane & 3) ^ ((lane >> 3) & 3);  // (srow>>1)&3 swizzle
    const u16* Bsel = csel ? B1w : B0w;

    f32x4 acc[4][4] = {};
    const int NT = (MODE == 0) ? 16 : 8;

    auto stage = [&](int buf, int tk) {
        const int kt = tk * 32;
        const u16* Asrc = (MODE == 0 && kt >= 256) ? A1 : A0;
        const u16* Bsrc = (MODE == 0) ? ((kt >= 256) ? B1w : B0w) : Bsel;
        const int  kb   = (MODE == 0 && kt >= 256) ? kt - 256 : kt;
        #pragma unroll
        for (int i = 0; i < 2; ++i) {
            int row = w * 32 + i * 16 + srow;
            gload_lds16(Asrc + (size_t)(row0 + row) * DIN + kb + sblk * 8,
                        &sA[buf][w * 1024 + i * 512]);
            gload_lds16(Bsrc + (size_t)(col0 + row) * DIN + kb + sblk * 8,
                        &sB[buf][w * 1024 + i * 512]);
        }
    };

    stage(0, 0);
    stage(1, 1);                 // 8 loads in flight per wave
    for (int tk = 0; tk < NT; ++tk) {
        const int cur = tk & 1;
        if (tk + 1 < NT) asm volatile("s_waitcnt vmcnt(4)" ::: "memory");
        else             asm volatile("s_waitcnt vmcnt(0)" ::: "memory");
        __builtin_amdgcn_sched_barrier(0);
        __builtin_amdgcn_s_barrier();         // buf[cur] complete for all waves

        bf16x8 af[4], bfr[4];
        #pragma unroll
        for (int m = 0; m < 4; ++m) {
            int row = wr * 64 + m * 16 + lr;
            af[m] = *(const bf16x8*)&sA[cur][row * 32 + 8 * (lg ^ ((lr >> 1) & 3))];
        }
        #pragma unroll
        for (int n = 0; n < 4; ++n) {
            int row = wc * 64 + n * 16 + lr;
            bfr[n] = *(const bf16x8*)&sB[cur][row * 32 + 8 * (lg ^ ((lr >> 1) & 3))];
        }
        #pragma unroll
        for (int m = 0; m < 4; ++m)
            #pragma unroll
            for (int n = 0; n < 4; ++n)
                acc[m][n] = __builtin_amdgcn_mfma_f32_16x16x32_bf16(af[m], bfr[n], acc[m][n], 0, 0, 0);

        asm volatile("s_waitcnt lgkmcnt(0)" ::: "memory");
        __builtin_amdgcn_sched_barrier(0);
        __builtin_amdgcn_s_barrier();
        if (tk + 2 < NT) stage(cur, tk + 2);
    }

    const bool f32out = (MODE == 1) && (csel == 1);
    #pragma unroll
    for (int m = 0; m < 4; ++m) {
        int row = row0 + wr * 64 + m * 16 + lg * 4;
        #pragma unroll
        for (int n = 0; n < 4; ++n) {
            int col = col0 + wc * 64 + n * 16 + lr;
            #pragma unroll
            for (int r = 0; r < 4; ++r) {
                float v = acc[m][n][r];
                if (MODE == 0) {
                    v += bias[col];
                    if (do_relu) v = fmaxf(v, 0.0f);
                    ((u16*)out0)[(size_t)(row + r) * dout + col] = f2b(v);
                    if (out8) out8[(size_t)(row + r) * dout + col] = f32_to_fp8(v);
                } else if (f32out) {
                    v += bias[col];
                    ((float*)out1)[(size_t)(row + r) * dout + col] = v;
                } else {
                    out8[(size_t)(row + r) * dout + col] = f32_to_fp8(v);
                }
            }
        }
    }
}

// ---------------- fused layer-2 agg + classifier: fp8 z2 rows (128B) ----------------
__launch_bounds__(256)
__global__ void aggcls_kernel(const int* __restrict__ rowptr, const int* __restrict__ rowend,
                              const int* __restrict__ csr_src, const float* __restrict__ rinv,
                              const u8* __restrict__ z28, const float* __restrict__ y2,
                              const float* __restrict__ Wc, const float* __restrict__ bc,
                              float* __restrict__ out) {
    __shared__ float sW[128];
    int t = threadIdx.x;
    if (t < 128) sW[t] = Wc[t];
    __syncthreads();
    int node = blockIdx.x * 16 + (t >> 4);
    int lane = t & 15;
    if (node >= N_NODES) return;
    int beg = rowptr[node];
    int end = rowend[node];
    const u8* zl = z28 + lane * 8;
    float a[8] = {};
    int p = beg;
    for (; p + 3 < end; p += 4) {
        int s0 = csr_src[p], s1 = csr_src[p + 1], s2 = csr_src[p + 2], s3 = csr_src[p + 3];
        uint2 v0 = *(const uint2*)(zl + (size_t)s0 * 128);
        uint2 v1 = *(const uint2*)(zl + (size_t)s1 * 128);
        uint2 v2 = *(const uint2*)(zl + (size_t)s2 * 128);
        uint2 v3 = *(const uint2*)(zl + (size_t)s3 * 128);
        accum8(a, v0); accum8(a, v1); accum8(a, v2); accum8(a, v3);
    }
    for (; p < end; ++p) {
        uint2 v0 = *(const uint2*)(zl + (size_t)csr_src[p] * 128);
        accum8(a, v0);
    }
    float r = rinv[node];
    float4 ylo = *(const float4*)(y2 + (size_t)node * 128 + lane * 8);
    float4 yhi = *(const float4*)(y2 + (size_t)node * 128 + lane * 8 + 4);
    float yv[8] = { ylo.x, ylo.y, ylo.z, ylo.w, yhi.x, yhi.y, yhi.z, yhi.w };
    float s = 0.f;
    #pragma unroll
    for (int j = 0; j < 8; ++j)
        s += (a[j] * r + yv[j]) * sW[lane * 8 + j];
    #pragma unroll
    for (int off = 8; off; off >>= 1) s += __shfl_xor(s, off, 16);
    if (lane == 0) {
        float z = s + bc[0];
        out[node] = 1.0f / (1.0f + expf(-z));
    }
}

extern "C" void kernel_launch(void* const* d_in, const int* in_sizes, int n_in,
                              void* d_out, int out_size, void* d_ws, size_t ws_size,
                              hipStream_t stream) {
    const float* x   = (const float*)d_in[0];
    const int*   ei  = (const int*)d_in[1];
    const float* Wl0 = (const float*)d_in[2];
    const float* Wr0 = (const float*)d_in[3];
    const float* b0  = (const float*)d_in[4];
    const float* Wl1 = (const float*)d_in[5];
    const float* Wr1 = (const float*)d_in[6];
    const float* b1  = (const float*)d_in[7];
    const float* Wl2 = (const float*)d_in[8];
    const float* Wr2 = (const float*)d_in[9];
    const float* b2  = (const float*)d_in[10];
    const float* Wc  = (const float*)d_in[11];
    const float* bc  = (const float*)d_in[12];
    float* out = (float*)d_out;

    const int* src = ei;
    const int* dst = ei + N_EDGES;

    // ---- workspace layout ----
    int*   MT     = (int*)d_ws;                    // MT_PAD
    int*   MTs    = MT + MT_PAD;                   // MT_PAD
    int*   bsums  = MTs + MT_PAD;                  // 1024
    u32*   csrtmp = (u32*)(bsums + 1024);          // N_EDGES
    int*   csr    = (int*)(csrtmp + N_EDGES);      // N_EDGES
    int*   rowptr = csr + N_EDGES;                 // N_PAD
    int*   rowend = rowptr + N_PAD;                // N_PAD
    float* rinv   = (float*)(rowend + N_PAD);      // N_PAD
    u16*   xb     = (u16*)(rinv + N_PAD);          // N_PAD*256 bf16
    u16*   wb     = xb + (size_t)N_PAD * 256;      // weights
    u16*   bufA   = wb + 327680;                   // agg (bf16)
    u16*   bufB   = bufA + (size_t)N_PAD * 256;    // h1 / y2(f32,128)
    u16*   bufC   = bufB + (size_t)N_PAD * 256;    // h2
    u8*    x8     = (u8*)(bufC + (size_t)N_PAD * 256);  // N_PAD*256 fp8
    u8*    h18    = x8 + (size_t)N_PAD * 256;           // N_PAD*256 fp8
    u8*    z28    = h18 + (size_t)N_PAD * 256;          // N_PAD*128 fp8

    u16* wl0 = wb;
    u16* wr0 = wl0 + 65536;
    u16* wl1 = wr0 + 65536;
    u16* wr1 = wl1 + 65536;
    u16* wl2 = wr1 + 65536;
    u16* wr2 = wl2 + 32768;

    // ---- conversions + histogram (hist blocks FIRST so they overlap cvt) ----
    const int xblocks = (N_NODES * 64 + 255) / 256;   // 25000
    cvt_hist_kernel<<<NC + 320 + xblocks, 256, 0, stream>>>(
        x, xb, x8, Wl0, Wr0, Wl1, Wr1, Wl2, Wr2,
        wl0, wr0, wl1, wr1, wl2, wr2, dst, MT);

    // ---- CSR build (scan1 blocks == bucket rows; carry folded into p2/p3) ----
    const int scan_blocks = MT_N / 256;            // 782 == NB
    scan1_kernel<<<scan_blocks, 256, 0, stream>>>(MT, MTs, bsums, MT_N);
    scan_carry_kernel<<<1, 256, 0, stream>>>(bsums, scan_blocks);
    p2_partition<<<NC, 256, 0, stream>>>(src, dst, MTs, bsums, csrtmp);
    p3_csr<<<NB, 256, 0, stream>>>(MTs, bsums, csrtmp, csr, rowptr, rowend, rinv);

    const int Mblocks = (N_NODES + 127) / 128;     // 782
    const int gemm_blocks = Mblocks * 2;           // 1564 (1D, xcd-chunked)
    const int agg_blocks = (N_NODES + 15) / 16;    // 6250

    // ---- layer 0 ----
    agg_kernel<<<agg_blocks, 256, 0, stream>>>(rowptr, rowend, csr, rinv, x8, bufA);
    sage_gemm<0><<<gemm_blocks, 256, 0, stream>>>(bufA, xb, wl0, wr0, b0, bufB, nullptr, h18, 256, 1);

    // ---- layer 1 ----
    agg_kernel<<<agg_blocks, 256, 0, stream>>>(rowptr, rowend, csr, rinv, h18, bufA);
    sage_gemm<0><<<gemm_blocks, 256, 0, stream>>>(bufA, bufB, wl1, wr1, b1, bufC, nullptr, nullptr, 256, 1);

    // ---- layer 2, projection-first (agg is linear) ----
    // csel=0: z2 = h2 @ Wl2^T -> fp8 z28 ; csel=1: y2 = h2 @ Wr2^T + b2 -> f32 bufB
    sage_gemm<1><<<gemm_blocks, 256, 0, stream>>>(bufC, nullptr, wl2, wr2, b2, nullptr, bufB, z28, 128, 0);
    // h3 = agg(z2)*rinv + y2, fused with classifier
    aggcls_kernel<<<agg_blocks, 256, 0, stream>>>(rowptr, rowend, csr, rinv,
                                                  z28, (const float*)bufB, Wc, bc, out);
}